// Round 4
// baseline (145.293 us; speedup 1.0000x reference)
//
#include <hip/hip_runtime.h>
#include <hip/hip_cooperative_groups.h>

#define NUM_TOKENS 16384
#define DIM 4096
#define NE 8
#define NSLOTS (NUM_TOKENS * 2)   // 32768
#define NB1 256                   // blocks (64 tokens / 128 slots each), 1 per CU

typedef unsigned long long u64;

__device__ __forceinline__ void onehot_add(u64& h0, u64& h1, int e) {
    if (e < 4) h0 += 1ull << (16 * e);
    else       h1 += 1ull << (16 * (e - 4));
}
__device__ __forceinline__ unsigned field_of(u64 h0, u64 h1, int e) {
    return (unsigned)(((e < 4) ? (h0 >> (16 * e)) : (h1 >> (16 * (e - 4)))) & 0xFFFFull);
}

// One cooperative kernel: gemv + sigmoid + top2 + rank  ->  grid.sync  ->
// global offsets (redundant 4 KiB scan per block) + scatter of own 128 slots.
__global__ __launch_bounds__(1024) void router_all(
    const float* __restrict__ x, const float* __restrict__ W,
    u64* __restrict__ bh_ws,      // [NB1][2] packed per-block histograms
    float* __restrict__ out)      // [32768 scores | 32768 token idx | 8 counts]
{
    __shared__ float4 Wlds[NE * (DIM / 4)];  // 128 KiB
    __shared__ int   eLds[128];              // expert id per local slot
    __shared__ float sLds[128];              // score per local slot

    const int tid = threadIdx.x;
    const int lane = tid & 63;
    const int wave = tid >> 6;
    const int b = blockIdx.x;
    const int tok0 = b * 64 + wave * 4;

    const float4* x4 = reinterpret_cast<const float4*>(x);
    const float4* xr0 = x4 + (size_t)(tok0 + 0) * (DIM / 4);
    const float4* xr1 = x4 + (size_t)(tok0 + 1) * (DIM / 4);
    const float4* xr2 = x4 + (size_t)(tok0 + 2) * (DIM / 4);
    const float4* xr3 = x4 + (size_t)(tok0 + 3) * (DIM / 4);

    // prefetch iteration-0 x before the staging barrier
    float4 p0 = xr0[lane];
    float4 p1 = xr1[lane];
    float4 p2 = xr2[lane];
    float4 p3 = xr3[lane];

    const float4* W4 = reinterpret_cast<const float4*>(W);
#pragma unroll
    for (int k = 0; k < 8; ++k)
        Wlds[tid + k * 1024] = W4[tid + k * 1024];
    __syncthreads();

    float a[32];
#pragma unroll
    for (int v = 0; v < 32; ++v) a[v] = 0.f;

#define GEMV_STEP(XA, XB, XC, XD, F4I)                                          \
    do {                                                                        \
        _Pragma("unroll")                                                       \
        for (int e = 0; e < 8; ++e) {                                           \
            float4 w = Wlds[e * 1024 + (F4I)];                                  \
            a[0*8+e] = fmaf((XA).w, w.w, fmaf((XA).z, w.z, fmaf((XA).y, w.y, fmaf((XA).x, w.x, a[0*8+e])))); \
            a[1*8+e] = fmaf((XB).w, w.w, fmaf((XB).z, w.z, fmaf((XB).y, w.y, fmaf((XB).x, w.x, a[1*8+e])))); \
            a[2*8+e] = fmaf((XC).w, w.w, fmaf((XC).z, w.z, fmaf((XC).y, w.y, fmaf((XC).x, w.x, a[2*8+e])))); \
            a[3*8+e] = fmaf((XD).w, w.w, fmaf((XD).z, w.z, fmaf((XD).y, w.y, fmaf((XD).x, w.x, a[3*8+e])))); \
        }                                                                       \
    } while (0)

    GEMV_STEP(p0, p1, p2, p3, lane);
#pragma unroll 3
    for (int it = 1; it < 16; ++it) {
        const int f4i = it * 64 + lane;
        float4 xa = xr0[f4i];
        float4 xb = xr1[f4i];
        float4 xc = xr2[f4i];
        float4 xd = xr3[f4i];
        GEMV_STEP(xa, xb, xc, xd, f4i);
    }

    // ---- merged butterfly: 32 values over 64 lanes, bit-identical add tree ----
#define MERGE(DST, A, B, BIT, DIST)                       \
    do {                                                  \
        const bool sel = (lane >> (BIT)) & 1;             \
        float _lo = sel ? (B) : (A);                      \
        float _hi = sel ? (A) : (B);                      \
        DST = _lo + __shfl_xor(_hi, (DIST), 64);          \
    } while (0)

    float m1[16], m2[8], m3[4], m4[2], m5;
#pragma unroll
    for (int i = 0; i < 16; ++i) MERGE(m1[i], a[2*i], a[2*i+1], 0, 1);
#pragma unroll
    for (int i = 0; i < 8; ++i)  MERGE(m2[i], m1[2*i], m1[2*i+1], 1, 2);
#pragma unroll
    for (int i = 0; i < 4; ++i)  MERGE(m3[i], m2[2*i], m2[2*i+1], 2, 4);
#pragma unroll
    for (int i = 0; i < 2; ++i)  MERGE(m4[i], m3[2*i], m3[2*i+1], 3, 8);
    MERGE(m5, m4[0], m4[1], 4, 16);
    m5 += __shfl_xor(m5, 32, 64);
    // lane L holds full sum of value v = L&31 : t = (L>>3)&3, e = L&7

    const float s = 1.0f / (1.0f + expf(-m5));

    // ---- top-2 tournament within each 8-lane group (ties -> lower index) ----
    float v1 = s; int e1 = lane & 7;
#pragma unroll
    for (int d = 1; d < 8; d <<= 1) {
        float ov = __shfl_xor(v1, d, 64);
        int   oe = __shfl_xor(e1, d, 64);
        const bool take = (ov > v1) || (ov == v1 && oe < e1);
        v1 = take ? ov : v1;
        e1 = take ? oe : e1;
    }
    float v2 = ((lane & 7) == e1) ? -1e30f : s; int e2 = lane & 7;
#pragma unroll
    for (int d = 1; d < 8; d <<= 1) {
        float ov = __shfl_xor(v2, d, 64);
        int   oe = __shfl_xor(e2, d, 64);
        const bool take = (ov > v2) || (ov == v2 && oe < e2);
        v2 = take ? ov : v2;
        e2 = take ? oe : e2;
    }

    if ((lane & 7) == 0 && lane < 32) {
        const int tl = wave * 4 + (lane >> 3);          // local token 0..63
        reinterpret_cast<float2*>(sLds)[tl] = make_float2(v1, v2);
        reinterpret_cast<int2*>(eLds)[tl]   = make_int2(e1, e2);
    }
    __syncthreads();

    // ---- wave 0: stable rank scan over this block's 128 slots ----
    int2 ee = make_int2(0, 0);
    unsigned rankA = 0, rankB = 0;
    if (wave == 0) {
        ee = reinterpret_cast<const int2*>(eLds)[lane];  // slots 2L, 2L+1
        u64 h0 = 0ull, h1 = 0ull;
        onehot_add(h0, h1, ee.x);
        onehot_add(h0, h1, ee.y);
        const u64 own0 = h0, own1 = h1;
#pragma unroll
        for (int d = 1; d < 64; d <<= 1) {
            u64 n0 = __shfl_up(h0, d, 64);
            u64 n1 = __shfl_up(h1, d, 64);
            if (lane >= d) { h0 += n0; h1 += n1; }
        }
        u64 ex0 = h0 - own0, ex1 = h1 - own1;
        rankA = field_of(ex0, ex1, ee.x);
        onehot_add(ex0, ex1, ee.x);
        rankB = field_of(ex0, ex1, ee.y);

        const u64 t0 = __shfl(h0, 63, 64);
        const u64 t1 = __shfl(h1, 63, 64);
        if (lane == 0) {
            bh_ws[2 * b + 0] = t0;
            bh_ws[2 * b + 1] = t1;
        }
    }

    __threadfence();
    cooperative_groups::this_grid().sync();

    // ---- phase 2 (wave 0 only): global offsets + scatter own 128 slots ----
    if (wave == 0) {
        const ulonglong2* bh2 = reinterpret_cast<const ulonglong2*>(bh_ws);
        const ulonglong2 hA = bh2[4 * lane + 0];   // lane owns blocks 4L..4L+3
        const ulonglong2 hB = bh2[4 * lane + 1];
        const ulonglong2 hC = bh2[4 * lane + 2];
        const ulonglong2 hD = bh2[4 * lane + 3];

        const u64 x1_0 = hA.x,         x1_1 = hA.y;        // excl. within lane
        const u64 x2_0 = x1_0 + hB.x,  x2_1 = x1_1 + hB.y;
        const u64 x3_0 = x2_0 + hC.x,  x3_1 = x2_1 + hC.y;
        const u64 inc0 = x3_0 + hD.x,  inc1 = x3_1 + hD.y;

        u64 s0 = inc0, s1 = inc1;
#pragma unroll
        for (int d = 1; d < 64; d <<= 1) {
            u64 n0 = __shfl_up(s0, d, 64);
            u64 n1 = __shfl_up(s1, d, 64);
            if (lane >= d) { s0 += n0; s1 += n1; }
        }
        const u64 base0 = s0 - inc0, base1 = s1 - inc1;   // excl. across lanes
        const u64 g0 = __shfl(s0, 63, 64);                // packed grand totals
        const u64 g1 = __shfl(s1, 63, 64);

        // packed expert exclusive bases
        unsigned t0e = (unsigned)((g0 >>  0) & 0xFFFF), t1e = (unsigned)((g0 >> 16) & 0xFFFF);
        unsigned t2e = (unsigned)((g0 >> 32) & 0xFFFF), t3e = (unsigned)((g0 >> 48) & 0xFFFF);
        unsigned t4e = (unsigned)((g1 >>  0) & 0xFFFF), t5e = (unsigned)((g1 >> 16) & 0xFFFF);
        unsigned t6e = (unsigned)((g1 >> 32) & 0xFFFF);
        unsigned b0 = 0, b1 = b0 + t0e, b2 = b1 + t1e, b3 = b2 + t2e;
        unsigned b4 = b3 + t3e, b5 = b4 + t4e, b6 = b5 + t5e, b7 = b6 + t6e;
        const u64 pb0 = (u64)b0 | ((u64)b1 << 16) | ((u64)b2 << 32) | ((u64)b3 << 48);
        const u64 pb1 = (u64)b4 | ((u64)b5 << 16) | ((u64)b6 << 32) | ((u64)b7 << 48);

        // this block's packed global offset pair (owner lane b>>2, slot b&3)
        const int owner = b >> 2, sub = b & 3;   // uniform
        u64 sel0, sel1;
        switch (sub) {
            case 0:  sel0 = base0 + pb0;        sel1 = base1 + pb1;        break;
            case 1:  sel0 = base0 + x1_0 + pb0; sel1 = base1 + x1_1 + pb1; break;
            case 2:  sel0 = base0 + x2_0 + pb0; sel1 = base1 + x2_1 + pb1; break;
            default: sel0 = base0 + x3_0 + pb0; sel1 = base1 + x3_1 + pb1; break;
        }
        const u64 o0 = __shfl(sel0, owner, 64);
        const u64 o1 = __shfl(sel1, owner, 64);

        if (b == 0 && lane < NE) {
            const unsigned tv = (unsigned)(((lane < 4) ? (g0 >> (16 * lane))
                                                       : (g1 >> (16 * (lane - 4)))) & 0xFFFFull);
            out[2 * NSLOTS + lane] = (float)tv;
        }

        // scatter own 2 slots
        const float2 sc = reinterpret_cast<const float2*>(sLds)[lane];
        const float tokf = (float)(b * 64 + lane);
        const unsigned pA = field_of(o0, o1, ee.x) + rankA;
        const unsigned pB = field_of(o0, o1, ee.y) + rankB;
        out[pA] = sc.x;
        out[NSLOTS + pA] = tokf;
        out[pB] = sc.y;
        out[NSLOTS + pB] = tokf;
    }
}

extern "C" void kernel_launch(void* const* d_in, const int* in_sizes, int n_in,
                              void* d_out, int out_size, void* d_ws, size_t ws_size,
                              hipStream_t stream) {
    const float* x = (const float*)d_in[0];
    const float* W = (const float*)d_in[1];
    float* out = (float*)d_out;
    u64* bh_ws = (u64*)d_ws;   // 4 KiB

    void* args[] = { (void*)&x, (void*)&W, (void*)&bh_ws, (void*)&out };
    hipLaunchCooperativeKernel(reinterpret_cast<void*>(router_all),
                               dim3(NB1), dim3(1024), args, 0, stream);
}

// Round 5
// 94.615 us; speedup vs baseline: 1.5356x; 1.5356x over previous
//
#include <hip/hip_runtime.h>

#define NUM_TOKENS 16384
#define DIM 4096
#define NE 8
#define NSLOTS (NUM_TOKENS * 2)   // 32768
#define NB1 256                   // blocks (64 tokens / 128 slots each), 1 per CU

typedef unsigned long long u64;

#define TAG_BYTE 0xA5ull
#define TAG (TAG_BYTE << 56)
#define UNTAG(v) ((v) & 0x00FFFFFFFFFFFFFFull)

__device__ __forceinline__ void onehot_add(u64& h0, u64& h1, int e) {
    if (e < 4) h0 += 1ull << (16 * e);
    else       h1 += 1ull << (16 * (e - 4));
}
__device__ __forceinline__ unsigned field_of(u64 h0, u64 h1, int e) {
    return (unsigned)(((e < 4) ? (h0 >> (16 * e)) : (h1 >> (16 * (e - 4)))) & 0xFFFFull);
}

// One kernel: gemv + sigmoid + top2 + rank -> inline flag barrier (no calls) ->
// redundant 4 KiB offset scan per block + scatter of own 128 slots.
__global__ __launch_bounds__(1024) void router_all(
    const float* __restrict__ x, const float* __restrict__ W,
    u64* bh_ws,                   // [NB1][2] packed per-block histograms (tagged)
    float* __restrict__ out)      // [32768 scores | 32768 token idx | 8 counts]
{
    __shared__ float4 Wlds[NE * (DIM / 4)];  // 128 KiB
    __shared__ int   eLds[128];
    __shared__ float sLds[128];

    const int tid = threadIdx.x;
    const int lane = tid & 63;
    const int wave = tid >> 6;
    const int b = blockIdx.x;
    const int tok0 = b * 64 + wave * 4;

    // clear our own publication slots (invalidate poison/garbage) ASAP
    if (tid == 0) {
        __hip_atomic_store(&bh_ws[2 * b + 0], 0ull, __ATOMIC_RELAXED, __HIP_MEMORY_SCOPE_AGENT);
        __hip_atomic_store(&bh_ws[2 * b + 1], 0ull, __ATOMIC_RELAXED, __HIP_MEMORY_SCOPE_AGENT);
    }

    const float4* x4 = reinterpret_cast<const float4*>(x);
    const float4* xr0 = x4 + (size_t)(tok0 + 0) * (DIM / 4);
    const float4* xr1 = x4 + (size_t)(tok0 + 1) * (DIM / 4);
    const float4* xr2 = x4 + (size_t)(tok0 + 2) * (DIM / 4);
    const float4* xr3 = x4 + (size_t)(tok0 + 3) * (DIM / 4);

    // prefetch iteration-0 x before the staging barrier
    float4 p0 = xr0[lane];
    float4 p1 = xr1[lane];
    float4 p2 = xr2[lane];
    float4 p3 = xr3[lane];

    const float4* W4 = reinterpret_cast<const float4*>(W);
#pragma unroll
    for (int k = 0; k < 8; ++k)
        Wlds[tid + k * 1024] = W4[tid + k * 1024];
    __syncthreads();

    float a[32];
#pragma unroll
    for (int v = 0; v < 32; ++v) a[v] = 0.f;

#define GEMV_STEP(XA, XB, XC, XD, F4I)                                          \
    do {                                                                        \
        _Pragma("unroll")                                                       \
        for (int e = 0; e < 8; ++e) {                                           \
            float4 w = Wlds[e * 1024 + (F4I)];                                  \
            a[0*8+e] = fmaf((XA).w, w.w, fmaf((XA).z, w.z, fmaf((XA).y, w.y, fmaf((XA).x, w.x, a[0*8+e])))); \
            a[1*8+e] = fmaf((XB).w, w.w, fmaf((XB).z, w.z, fmaf((XB).y, w.y, fmaf((XB).x, w.x, a[1*8+e])))); \
            a[2*8+e] = fmaf((XC).w, w.w, fmaf((XC).z, w.z, fmaf((XC).y, w.y, fmaf((XC).x, w.x, a[2*8+e])))); \
            a[3*8+e] = fmaf((XD).w, w.w, fmaf((XD).z, w.z, fmaf((XD).y, w.y, fmaf((XD).x, w.x, a[3*8+e])))); \
        }                                                                       \
    } while (0)

    GEMV_STEP(p0, p1, p2, p3, lane);
#pragma unroll 3
    for (int it = 1; it < 16; ++it) {
        const int f4i = it * 64 + lane;
        float4 xa = xr0[f4i];
        float4 xb = xr1[f4i];
        float4 xc = xr2[f4i];
        float4 xd = xr3[f4i];
        GEMV_STEP(xa, xb, xc, xd, f4i);
    }

    // ---- merged butterfly: 32 values over 64 lanes, bit-identical add tree ----
#define MERGE(DST, A, B, BIT, DIST)                       \
    do {                                                  \
        const bool sel = (lane >> (BIT)) & 1;             \
        float _lo = sel ? (B) : (A);                      \
        float _hi = sel ? (A) : (B);                      \
        DST = _lo + __shfl_xor(_hi, (DIST), 64);          \
    } while (0)

    float m1[16], m2[8], m3[4], m4[2], m5;
#pragma unroll
    for (int i = 0; i < 16; ++i) MERGE(m1[i], a[2*i], a[2*i+1], 0, 1);
#pragma unroll
    for (int i = 0; i < 8; ++i)  MERGE(m2[i], m1[2*i], m1[2*i+1], 1, 2);
#pragma unroll
    for (int i = 0; i < 4; ++i)  MERGE(m3[i], m2[2*i], m2[2*i+1], 2, 4);
#pragma unroll
    for (int i = 0; i < 2; ++i)  MERGE(m4[i], m3[2*i], m3[2*i+1], 3, 8);
    MERGE(m5, m4[0], m4[1], 4, 16);
    m5 += __shfl_xor(m5, 32, 64);
    // lane L holds full sum of value v = L&31 : t = (L>>3)&3, e = L&7

    const float s = 1.0f / (1.0f + expf(-m5));

    // ---- top-2 tournament within each 8-lane group (ties -> lower index) ----
    float v1 = s; int e1 = lane & 7;
#pragma unroll
    for (int d = 1; d < 8; d <<= 1) {
        float ov = __shfl_xor(v1, d, 64);
        int   oe = __shfl_xor(e1, d, 64);
        const bool take = (ov > v1) || (ov == v1 && oe < e1);
        v1 = take ? ov : v1;
        e1 = take ? oe : e1;
    }
    float v2 = ((lane & 7) == e1) ? -1e30f : s; int e2 = lane & 7;
#pragma unroll
    for (int d = 1; d < 8; d <<= 1) {
        float ov = __shfl_xor(v2, d, 64);
        int   oe = __shfl_xor(e2, d, 64);
        const bool take = (ov > v2) || (ov == v2 && oe < e2);
        v2 = take ? ov : v2;
        e2 = take ? oe : e2;
    }

    if ((lane & 7) == 0 && lane < 32) {
        const int tl = wave * 4 + (lane >> 3);          // local token 0..63
        reinterpret_cast<float2*>(sLds)[tl] = make_float2(v1, v2);
        reinterpret_cast<int2*>(eLds)[tl]   = make_int2(e1, e2);
    }
    __syncthreads();

    if (wave != 0) return;   // waves 1..15 done; wave 0 finishes the block

    // ---- stable rank scan over this block's 128 slots ----
    const int2 ee = reinterpret_cast<const int2*>(eLds)[lane];  // slots 2L, 2L+1
    u64 h0 = 0ull, h1 = 0ull;
    onehot_add(h0, h1, ee.x);
    onehot_add(h0, h1, ee.y);
    const u64 own0 = h0, own1 = h1;
#pragma unroll
    for (int d = 1; d < 64; d <<= 1) {
        u64 n0 = __shfl_up(h0, d, 64);
        u64 n1 = __shfl_up(h1, d, 64);
        if (lane >= d) { h0 += n0; h1 += n1; }
    }
    u64 ex0 = h0 - own0, ex1 = h1 - own1;
    const unsigned rankA = field_of(ex0, ex1, ee.x);
    onehot_add(ex0, ex1, ee.x);
    const unsigned rankB = field_of(ex0, ex1, ee.y);

    // ---- publish tagged histogram (counts <= 128, top byte free) ----
    const u64 t0 = __shfl(h0, 63, 64);
    const u64 t1 = __shfl(h1, 63, 64);
    if (lane == 0) {
        __hip_atomic_store(&bh_ws[2 * b + 0], t0 | TAG, __ATOMIC_RELEASE, __HIP_MEMORY_SCOPE_AGENT);
        __hip_atomic_store(&bh_ws[2 * b + 1], t1 | TAG, __ATOMIC_RELEASE, __HIP_MEMORY_SCOPE_AGENT);
    }

    // ---- inline flag barrier: lane L spins on blocks 4L..4L+3 ----
    u64 hv0[4], hv1[4];
#pragma unroll
    for (int j = 0; j < 4; ++j) {
        const int blk = 4 * lane + j;
        u64 v0, v1x;
        do { v0  = __hip_atomic_load(&bh_ws[2 * blk + 0], __ATOMIC_ACQUIRE, __HIP_MEMORY_SCOPE_AGENT); }
        while ((v0 >> 56) != TAG_BYTE);
        do { v1x = __hip_atomic_load(&bh_ws[2 * blk + 1], __ATOMIC_ACQUIRE, __HIP_MEMORY_SCOPE_AGENT); }
        while ((v1x >> 56) != TAG_BYTE);
        hv0[j] = UNTAG(v0);
        hv1[j] = UNTAG(v1x);
    }

    // ---- global offsets (redundant per-block scan of 256 histograms) ----
    const u64 x1_0 = hv0[0],        x1_1 = hv1[0];        // excl. within lane
    const u64 x2_0 = x1_0 + hv0[1], x2_1 = x1_1 + hv1[1];
    const u64 x3_0 = x2_0 + hv0[2], x3_1 = x2_1 + hv1[2];
    const u64 inc0 = x3_0 + hv0[3], inc1 = x3_1 + hv1[3];

    u64 s0 = inc0, s1 = inc1;
#pragma unroll
    for (int d = 1; d < 64; d <<= 1) {
        u64 n0 = __shfl_up(s0, d, 64);
        u64 n1 = __shfl_up(s1, d, 64);
        if (lane >= d) { s0 += n0; s1 += n1; }
    }
    const u64 base0 = s0 - inc0, base1 = s1 - inc1;   // excl. across lanes
    const u64 g0 = __shfl(s0, 63, 64);                // packed grand totals
    const u64 g1 = __shfl(s1, 63, 64);

    // packed expert exclusive bases
    unsigned t0e = (unsigned)((g0 >>  0) & 0xFFFF), t1e = (unsigned)((g0 >> 16) & 0xFFFF);
    unsigned t2e = (unsigned)((g0 >> 32) & 0xFFFF), t3e = (unsigned)((g0 >> 48) & 0xFFFF);
    unsigned t4e = (unsigned)((g1 >>  0) & 0xFFFF), t5e = (unsigned)((g1 >> 16) & 0xFFFF);
    unsigned t6e = (unsigned)((g1 >> 32) & 0xFFFF);
    unsigned b0 = 0, b1 = b0 + t0e, b2 = b1 + t1e, b3 = b2 + t2e;
    unsigned b4 = b3 + t3e, b5 = b4 + t4e, b6 = b5 + t5e, b7 = b6 + t6e;
    const u64 pb0 = (u64)b0 | ((u64)b1 << 16) | ((u64)b2 << 32) | ((u64)b3 << 48);
    const u64 pb1 = (u64)b4 | ((u64)b5 << 16) | ((u64)b6 << 32) | ((u64)b7 << 48);

    // this block's packed global offset pair (owner lane b>>2, slot b&3)
    const int owner = b >> 2, sub = b & 3;   // uniform
    u64 sel0, sel1;
    switch (sub) {
        case 0:  sel0 = base0 + pb0;        sel1 = base1 + pb1;        break;
        case 1:  sel0 = base0 + x1_0 + pb0; sel1 = base1 + x1_1 + pb1; break;
        case 2:  sel0 = base0 + x2_0 + pb0; sel1 = base1 + x2_1 + pb1; break;
        default: sel0 = base0 + x3_0 + pb0; sel1 = base1 + x3_1 + pb1; break;
    }
    const u64 o0 = __shfl(sel0, owner, 64);
    const u64 o1 = __shfl(sel1, owner, 64);

    if (b == 0 && lane < NE) {
        const unsigned tv = (unsigned)(((lane < 4) ? (g0 >> (16 * lane))
                                                   : (g1 >> (16 * (lane - 4)))) & 0xFFFFull);
        out[2 * NSLOTS + lane] = (float)tv;
    }

    // ---- scatter own 2 slots ----
    const float2 sc = reinterpret_cast<const float2*>(sLds)[lane];
    const float tokf = (float)(b * 64 + lane);
    const unsigned pA = field_of(o0, o1, ee.x) + rankA;
    const unsigned pB = field_of(o0, o1, ee.y) + rankB;
    out[pA] = sc.x;
    out[NSLOTS + pA] = tokf;
    out[pB] = sc.y;
    out[NSLOTS + pB] = tokf;
}

extern "C" void kernel_launch(void* const* d_in, const int* in_sizes, int n_in,
                              void* d_out, int out_size, void* d_ws, size_t ws_size,
                              hipStream_t stream) {
    const float* x = (const float*)d_in[0];
    const float* W = (const float*)d_in[1];
    float* out = (float*)d_out;
    u64* bh_ws = (u64*)d_ws;   // 4 KiB

    void* args[] = { (void*)&x, (void*)&W, (void*)&bh_ws, (void*)&out };
    hipLaunchCooperativeKernel(reinterpret_cast<void*>(router_all),
                               dim3(NB1), dim3(1024), args, 0, stream);
}

// Round 6
// 78.458 us; speedup vs baseline: 1.8518x; 1.2059x over previous
//
#include <hip/hip_runtime.h>

#define NUM_TOKENS 16384
#define DIM 4096
#define NE 8
#define NSLOTS (NUM_TOKENS * 2)   // 32768
#define NB1 256                   // blocks (64 tokens / 128 slots each), 1 per CU

typedef unsigned long long u64;

#define TAG_BYTE 0xA5ull
#define TAG (TAG_BYTE << 56)
#define UNTAG(v) ((v) & 0x00FFFFFFFFFFFFFFull)

__device__ __forceinline__ void onehot_add(u64& h0, u64& h1, int e) {
    if (e < 4) h0 += 1ull << (16 * e);
    else       h1 += 1ull << (16 * (e - 4));
}
__device__ __forceinline__ unsigned field_of(u64 h0, u64 h1, int e) {
    return (unsigned)(((e < 4) ? (h0 >> (16 * e)) : (h1 >> (16 * (e - 4)))) & 0xFFFFull);
}

// One kernel (NORMAL launch): gemv + sigmoid + top2 + rank -> inline flag
// barrier -> redundant 4 KiB offset scan per block + scatter of own 128 slots.
// Co-residency: 128 KiB LDS => 1 block/CU; 256 blocks on 256 CUs.
// bh_ws is zeroed by hipMemsetAsync before each launch, so only tagged
// values published THIS call can pass the spin check.
__global__ __launch_bounds__(1024) void router_all(
    const float* __restrict__ x, const float* __restrict__ W,
    u64* bh_ws,                   // [NB1][2] packed per-block histograms (tagged)
    float* __restrict__ out)      // [32768 scores | 32768 token idx | 8 counts]
{
    __shared__ float4 Wlds[NE * (DIM / 4)];  // 128 KiB
    __shared__ int   eLds[128];
    __shared__ float sLds[128];

    const int tid = threadIdx.x;
    const int lane = tid & 63;
    const int wave = tid >> 6;
    const int b = blockIdx.x;
    const int tok0 = b * 64 + wave * 4;

    const float4* x4 = reinterpret_cast<const float4*>(x);
    const float4* xr0 = x4 + (size_t)(tok0 + 0) * (DIM / 4);
    const float4* xr1 = x4 + (size_t)(tok0 + 1) * (DIM / 4);
    const float4* xr2 = x4 + (size_t)(tok0 + 2) * (DIM / 4);
    const float4* xr3 = x4 + (size_t)(tok0 + 3) * (DIM / 4);

    // prefetch iteration-0 x before the staging barrier
    float4 p0 = xr0[lane];
    float4 p1 = xr1[lane];
    float4 p2 = xr2[lane];
    float4 p3 = xr3[lane];

    const float4* W4 = reinterpret_cast<const float4*>(W);
#pragma unroll
    for (int k = 0; k < 8; ++k)
        Wlds[tid + k * 1024] = W4[tid + k * 1024];
    __syncthreads();

    float a[32];
#pragma unroll
    for (int v = 0; v < 32; ++v) a[v] = 0.f;

#define GEMV_STEP(XA, XB, XC, XD, F4I)                                          \
    do {                                                                        \
        _Pragma("unroll")                                                       \
        for (int e = 0; e < 8; ++e) {                                           \
            float4 w = Wlds[e * 1024 + (F4I)];                                  \
            a[0*8+e] = fmaf((XA).w, w.w, fmaf((XA).z, w.z, fmaf((XA).y, w.y, fmaf((XA).x, w.x, a[0*8+e])))); \
            a[1*8+e] = fmaf((XB).w, w.w, fmaf((XB).z, w.z, fmaf((XB).y, w.y, fmaf((XB).x, w.x, a[1*8+e])))); \
            a[2*8+e] = fmaf((XC).w, w.w, fmaf((XC).z, w.z, fmaf((XC).y, w.y, fmaf((XC).x, w.x, a[2*8+e])))); \
            a[3*8+e] = fmaf((XD).w, w.w, fmaf((XD).z, w.z, fmaf((XD).y, w.y, fmaf((XD).x, w.x, a[3*8+e])))); \
        }                                                                       \
    } while (0)

    GEMV_STEP(p0, p1, p2, p3, lane);
#pragma unroll 3
    for (int it = 1; it < 16; ++it) {
        const int f4i = it * 64 + lane;
        float4 xa = xr0[f4i];
        float4 xb = xr1[f4i];
        float4 xc = xr2[f4i];
        float4 xd = xr3[f4i];
        GEMV_STEP(xa, xb, xc, xd, f4i);
    }

    // ---- merged butterfly: 32 values over 64 lanes, bit-identical add tree ----
#define MERGE(DST, A, B, BIT, DIST)                       \
    do {                                                  \
        const bool sel = (lane >> (BIT)) & 1;             \
        float _lo = sel ? (B) : (A);                      \
        float _hi = sel ? (A) : (B);                      \
        DST = _lo + __shfl_xor(_hi, (DIST), 64);          \
    } while (0)

    float m1[16], m2[8], m3[4], m4[2], m5;
#pragma unroll
    for (int i = 0; i < 16; ++i) MERGE(m1[i], a[2*i], a[2*i+1], 0, 1);
#pragma unroll
    for (int i = 0; i < 8; ++i)  MERGE(m2[i], m1[2*i], m1[2*i+1], 1, 2);
#pragma unroll
    for (int i = 0; i < 4; ++i)  MERGE(m3[i], m2[2*i], m2[2*i+1], 2, 4);
#pragma unroll
    for (int i = 0; i < 2; ++i)  MERGE(m4[i], m3[2*i], m3[2*i+1], 3, 8);
    MERGE(m5, m4[0], m4[1], 4, 16);
    m5 += __shfl_xor(m5, 32, 64);
    // lane L holds full sum of value v = L&31 : t = (L>>3)&3, e = L&7

    const float s = 1.0f / (1.0f + expf(-m5));

    // ---- top-2 tournament within each 8-lane group (ties -> lower index) ----
    float v1 = s; int e1 = lane & 7;
#pragma unroll
    for (int d = 1; d < 8; d <<= 1) {
        float ov = __shfl_xor(v1, d, 64);
        int   oe = __shfl_xor(e1, d, 64);
        const bool take = (ov > v1) || (ov == v1 && oe < e1);
        v1 = take ? ov : v1;
        e1 = take ? oe : e1;
    }
    float v2 = ((lane & 7) == e1) ? -1e30f : s; int e2 = lane & 7;
#pragma unroll
    for (int d = 1; d < 8; d <<= 1) {
        float ov = __shfl_xor(v2, d, 64);
        int   oe = __shfl_xor(e2, d, 64);
        const bool take = (ov > v2) || (ov == v2 && oe < e2);
        v2 = take ? ov : v2;
        e2 = take ? oe : e2;
    }

    if ((lane & 7) == 0 && lane < 32) {
        const int tl = wave * 4 + (lane >> 3);          // local token 0..63
        reinterpret_cast<float2*>(sLds)[tl] = make_float2(v1, v2);
        reinterpret_cast<int2*>(eLds)[tl]   = make_int2(e1, e2);
    }
    __syncthreads();

    if (wave != 0) return;   // waves 1..15 done; wave 0 finishes the block

    // ---- stable rank scan over this block's 128 slots ----
    const int2 ee = reinterpret_cast<const int2*>(eLds)[lane];  // slots 2L, 2L+1
    u64 h0 = 0ull, h1 = 0ull;
    onehot_add(h0, h1, ee.x);
    onehot_add(h0, h1, ee.y);
    const u64 own0 = h0, own1 = h1;
#pragma unroll
    for (int d = 1; d < 64; d <<= 1) {
        u64 n0 = __shfl_up(h0, d, 64);
        u64 n1 = __shfl_up(h1, d, 64);
        if (lane >= d) { h0 += n0; h1 += n1; }
    }
    u64 ex0 = h0 - own0, ex1 = h1 - own1;
    const unsigned rankA = field_of(ex0, ex1, ee.x);
    onehot_add(ex0, ex1, ee.x);
    const unsigned rankB = field_of(ex0, ex1, ee.y);

    // ---- publish tagged histogram (counts <= 128, top byte free) ----
    const u64 t0 = __shfl(h0, 63, 64);
    const u64 t1 = __shfl(h1, 63, 64);
    if (lane == 0) {
        __hip_atomic_store(&bh_ws[2 * b + 0], t0 | TAG, __ATOMIC_RELEASE, __HIP_MEMORY_SCOPE_AGENT);
        __hip_atomic_store(&bh_ws[2 * b + 1], t1 | TAG, __ATOMIC_RELEASE, __HIP_MEMORY_SCOPE_AGENT);
    }

    // ---- inline flag barrier: lane L spins on blocks 4L..4L+3 ----
    u64 hv0[4], hv1[4];
#pragma unroll
    for (int j = 0; j < 4; ++j) {
        const int blk = 4 * lane + j;
        u64 v0, v1x;
        do { v0  = __hip_atomic_load(&bh_ws[2 * blk + 0], __ATOMIC_ACQUIRE, __HIP_MEMORY_SCOPE_AGENT); }
        while ((v0 >> 56) != TAG_BYTE);
        do { v1x = __hip_atomic_load(&bh_ws[2 * blk + 1], __ATOMIC_ACQUIRE, __HIP_MEMORY_SCOPE_AGENT); }
        while ((v1x >> 56) != TAG_BYTE);
        hv0[j] = UNTAG(v0);
        hv1[j] = UNTAG(v1x);
    }

    // ---- global offsets (redundant per-block scan of 256 histograms) ----
    const u64 x1_0 = hv0[0],        x1_1 = hv1[0];        // excl. within lane
    const u64 x2_0 = x1_0 + hv0[1], x2_1 = x1_1 + hv1[1];
    const u64 x3_0 = x2_0 + hv0[2], x3_1 = x2_1 + hv1[2];
    const u64 inc0 = x3_0 + hv0[3], inc1 = x3_1 + hv1[3];

    u64 s0 = inc0, s1 = inc1;
#pragma unroll
    for (int d = 1; d < 64; d <<= 1) {
        u64 n0 = __shfl_up(s0, d, 64);
        u64 n1 = __shfl_up(s1, d, 64);
        if (lane >= d) { s0 += n0; s1 += n1; }
    }
    const u64 base0 = s0 - inc0, base1 = s1 - inc1;   // excl. across lanes
    const u64 g0 = __shfl(s0, 63, 64);                // packed grand totals
    const u64 g1 = __shfl(s1, 63, 64);

    // packed expert exclusive bases
    unsigned t0e = (unsigned)((g0 >>  0) & 0xFFFF), t1e = (unsigned)((g0 >> 16) & 0xFFFF);
    unsigned t2e = (unsigned)((g0 >> 32) & 0xFFFF), t3e = (unsigned)((g0 >> 48) & 0xFFFF);
    unsigned t4e = (unsigned)((g1 >>  0) & 0xFFFF), t5e = (unsigned)((g1 >> 16) & 0xFFFF);
    unsigned t6e = (unsigned)((g1 >> 32) & 0xFFFF);
    unsigned b0 = 0, b1 = b0 + t0e, b2 = b1 + t1e, b3 = b2 + t2e;
    unsigned b4 = b3 + t3e, b5 = b4 + t4e, b6 = b5 + t5e, b7 = b6 + t6e;
    const u64 pb0 = (u64)b0 | ((u64)b1 << 16) | ((u64)b2 << 32) | ((u64)b3 << 48);
    const u64 pb1 = (u64)b4 | ((u64)b5 << 16) | ((u64)b6 << 32) | ((u64)b7 << 48);

    // this block's packed global offset pair (owner lane b>>2, slot b&3)
    const int owner = b >> 2, sub = b & 3;   // uniform
    u64 sel0, sel1;
    switch (sub) {
        case 0:  sel0 = base0 + pb0;        sel1 = base1 + pb1;        break;
        case 1:  sel0 = base0 + x1_0 + pb0; sel1 = base1 + x1_1 + pb1; break;
        case 2:  sel0 = base0 + x2_0 + pb0; sel1 = base1 + x2_1 + pb1; break;
        default: sel0 = base0 + x3_0 + pb0; sel1 = base1 + x3_1 + pb1; break;
    }
    const u64 o0 = __shfl(sel0, owner, 64);
    const u64 o1 = __shfl(sel1, owner, 64);

    if (b == 0 && lane < NE) {
        const unsigned tv = (unsigned)(((lane < 4) ? (g0 >> (16 * lane))
                                                   : (g1 >> (16 * (lane - 4)))) & 0xFFFFull);
        out[2 * NSLOTS + lane] = (float)tv;
    }

    // ---- scatter own 2 slots ----
    const float2 sc = reinterpret_cast<const float2*>(sLds)[lane];
    const float tokf = (float)(b * 64 + lane);
    const unsigned pA = field_of(o0, o1, ee.x) + rankA;
    const unsigned pB = field_of(o0, o1, ee.y) + rankB;
    out[pA] = sc.x;
    out[NSLOTS + pA] = tokf;
    out[pB] = sc.y;
    out[NSLOTS + pB] = tokf;
}

extern "C" void kernel_launch(void* const* d_in, const int* in_sizes, int n_in,
                              void* d_out, int out_size, void* d_ws, size_t ws_size,
                              hipStream_t stream) {
    const float* x = (const float*)d_in[0];
    const float* W = (const float*)d_in[1];
    float* out = (float*)d_out;
    u64* bh_ws = (u64*)d_ws;   // 4 KiB

    // deterministically clear the flag array each call (graph-capturable)
    hipMemsetAsync(bh_ws, 0, 2 * NB1 * sizeof(u64), stream);
    router_all<<<dim3(NB1), dim3(1024), 0, stream>>>(x, W, bh_ws, out);
}

// Round 7
// 73.780 us; speedup vs baseline: 1.9693x; 1.0634x over previous
//
#include <hip/hip_runtime.h>

#define NUM_TOKENS 16384
#define DIM 4096
#define NE 8
#define NSLOTS (NUM_TOKENS * 2)   // 32768
#define NB1 256                   // blocks (64 tokens / 128 slots each), 1 per CU

typedef unsigned long long u64;

__device__ __forceinline__ void onehot_add(u64& h0, u64& h1, int e) {
    if (e < 4) h0 += 1ull << (16 * e);
    else       h1 += 1ull << (16 * (e - 4));
}
__device__ __forceinline__ unsigned field_of(u64 h0, u64 h1, int e) {
    return (unsigned)(((e < 4) ? (h0 >> (16 * e)) : (h1 >> (16 * (e - 4)))) & 0xFFFFull);
}

// One kernel (normal launch): gemv + sigmoid + top2 + rank -> counter barrier
// (single-lane spin w/ s_sleep backoff) -> redundant 4 KiB offset scan per
// block + scatter of own 128 slots.
// Co-residency: 128 KiB LDS => 1 block/CU; 256 blocks on 256 CUs.
// bh_ws[0..511] = per-block packed histograms; bh_ws[512] = arrival counter.
// All zeroed by hipMemsetAsync before each launch.
__global__ __launch_bounds__(1024) void router_all(
    const float* __restrict__ x, const float* __restrict__ W,
    u64* bh_ws,
    float* __restrict__ out)      // [32768 scores | 32768 token idx | 8 counts]
{
    __shared__ float4 Wlds[NE * (DIM / 4)];  // 128 KiB
    __shared__ int   eLds[128];
    __shared__ float sLds[128];

    const int tid = threadIdx.x;
    const int lane = tid & 63;
    const int wave = tid >> 6;
    const int b = blockIdx.x;
    const int tok0 = b * 64 + wave * 4;

    const float4* x4 = reinterpret_cast<const float4*>(x);
    const float4* xr0 = x4 + (size_t)(tok0 + 0) * (DIM / 4);
    const float4* xr1 = x4 + (size_t)(tok0 + 1) * (DIM / 4);
    const float4* xr2 = x4 + (size_t)(tok0 + 2) * (DIM / 4);
    const float4* xr3 = x4 + (size_t)(tok0 + 3) * (DIM / 4);

    // prefetch iteration-0 x before the staging barrier
    float4 p0 = xr0[lane];
    float4 p1 = xr1[lane];
    float4 p2 = xr2[lane];
    float4 p3 = xr3[lane];

    const float4* W4 = reinterpret_cast<const float4*>(W);
#pragma unroll
    for (int k = 0; k < 8; ++k)
        Wlds[tid + k * 1024] = W4[tid + k * 1024];
    __syncthreads();

    float a[32];
#pragma unroll
    for (int v = 0; v < 32; ++v) a[v] = 0.f;

#define GEMV_STEP(XA, XB, XC, XD, F4I)                                          \
    do {                                                                        \
        _Pragma("unroll")                                                       \
        for (int e = 0; e < 8; ++e) {                                           \
            float4 w = Wlds[e * 1024 + (F4I)];                                  \
            a[0*8+e] = fmaf((XA).w, w.w, fmaf((XA).z, w.z, fmaf((XA).y, w.y, fmaf((XA).x, w.x, a[0*8+e])))); \
            a[1*8+e] = fmaf((XB).w, w.w, fmaf((XB).z, w.z, fmaf((XB).y, w.y, fmaf((XB).x, w.x, a[1*8+e])))); \
            a[2*8+e] = fmaf((XC).w, w.w, fmaf((XC).z, w.z, fmaf((XC).y, w.y, fmaf((XC).x, w.x, a[2*8+e])))); \
            a[3*8+e] = fmaf((XD).w, w.w, fmaf((XD).z, w.z, fmaf((XD).y, w.y, fmaf((XD).x, w.x, a[3*8+e])))); \
        }                                                                       \
    } while (0)

    GEMV_STEP(p0, p1, p2, p3, lane);
#pragma unroll 3
    for (int it = 1; it < 16; ++it) {
        const int f4i = it * 64 + lane;
        float4 xa = xr0[f4i];
        float4 xb = xr1[f4i];
        float4 xc = xr2[f4i];
        float4 xd = xr3[f4i];
        GEMV_STEP(xa, xb, xc, xd, f4i);
    }

    // ---- merged butterfly: 32 values over 64 lanes, bit-identical add tree ----
#define MERGE(DST, A, B, BIT, DIST)                       \
    do {                                                  \
        const bool sel = (lane >> (BIT)) & 1;             \
        float _lo = sel ? (B) : (A);                      \
        float _hi = sel ? (A) : (B);                      \
        DST = _lo + __shfl_xor(_hi, (DIST), 64);          \
    } while (0)

    float m1[16], m2[8], m3[4], m4[2], m5;
#pragma unroll
    for (int i = 0; i < 16; ++i) MERGE(m1[i], a[2*i], a[2*i+1], 0, 1);
#pragma unroll
    for (int i = 0; i < 8; ++i)  MERGE(m2[i], m1[2*i], m1[2*i+1], 1, 2);
#pragma unroll
    for (int i = 0; i < 4; ++i)  MERGE(m3[i], m2[2*i], m2[2*i+1], 2, 4);
#pragma unroll
    for (int i = 0; i < 2; ++i)  MERGE(m4[i], m3[2*i], m3[2*i+1], 3, 8);
    MERGE(m5, m4[0], m4[1], 4, 16);
    m5 += __shfl_xor(m5, 32, 64);
    // lane L holds full sum of value v = L&31 : t = (L>>3)&3, e = L&7

    const float s = 1.0f / (1.0f + expf(-m5));

    // ---- top-2 tournament within each 8-lane group (ties -> lower index) ----
    float v1 = s; int e1 = lane & 7;
#pragma unroll
    for (int d = 1; d < 8; d <<= 1) {
        float ov = __shfl_xor(v1, d, 64);
        int   oe = __shfl_xor(e1, d, 64);
        const bool take = (ov > v1) || (ov == v1 && oe < e1);
        v1 = take ? ov : v1;
        e1 = take ? oe : e1;
    }
    float v2 = ((lane & 7) == e1) ? -1e30f : s; int e2 = lane & 7;
#pragma unroll
    for (int d = 1; d < 8; d <<= 1) {
        float ov = __shfl_xor(v2, d, 64);
        int   oe = __shfl_xor(e2, d, 64);
        const bool take = (ov > v2) || (ov == v2 && oe < e2);
        v2 = take ? ov : v2;
        e2 = take ? oe : e2;
    }

    if ((lane & 7) == 0 && lane < 32) {
        const int tl = wave * 4 + (lane >> 3);          // local token 0..63
        reinterpret_cast<float2*>(sLds)[tl] = make_float2(v1, v2);
        reinterpret_cast<int2*>(eLds)[tl]   = make_int2(e1, e2);
    }
    __syncthreads();

    if (wave != 0) return;   // waves 1..15 done; wave 0 finishes the block

    // ---- stable rank scan over this block's 128 slots ----
    const int2 ee = reinterpret_cast<const int2*>(eLds)[lane];  // slots 2L, 2L+1
    u64 h0 = 0ull, h1 = 0ull;
    onehot_add(h0, h1, ee.x);
    onehot_add(h0, h1, ee.y);
    const u64 own0 = h0, own1 = h1;
#pragma unroll
    for (int d = 1; d < 64; d <<= 1) {
        u64 n0 = __shfl_up(h0, d, 64);
        u64 n1 = __shfl_up(h1, d, 64);
        if (lane >= d) { h0 += n0; h1 += n1; }
    }
    u64 ex0 = h0 - own0, ex1 = h1 - own1;
    const unsigned rankA = field_of(ex0, ex1, ee.x);
    onehot_add(ex0, ex1, ee.x);
    const unsigned rankB = field_of(ex0, ex1, ee.y);

    // ---- publish histogram + arrive at counter (release) ----
    const u64 t0 = __shfl(h0, 63, 64);
    const u64 t1 = __shfl(h1, 63, 64);
    u64* ctr = &bh_ws[2 * NB1];
    if (lane == 0) {
        __hip_atomic_store(&bh_ws[2 * b + 0], t0, __ATOMIC_RELAXED, __HIP_MEMORY_SCOPE_AGENT);
        __hip_atomic_store(&bh_ws[2 * b + 1], t1, __ATOMIC_RELAXED, __HIP_MEMORY_SCOPE_AGENT);
        __hip_atomic_fetch_add(ctr, 1ull, __ATOMIC_RELEASE, __HIP_MEMORY_SCOPE_AGENT);
        // single-lane spin, sleep backoff: 8 B/poll, no fabric storm
        while (__hip_atomic_load(ctr, __ATOMIC_ACQUIRE, __HIP_MEMORY_SCOPE_AGENT) != (u64)NB1)
            __builtin_amdgcn_s_sleep(4);
    }
    __builtin_amdgcn_fence(__ATOMIC_ACQUIRE, "agent");

    // ---- global offsets (redundant per-block scan of 256 histograms) ----
    const ulonglong2* bh2 = reinterpret_cast<const ulonglong2*>(bh_ws);
    const ulonglong2 hA = bh2[4 * lane + 0];   // lane owns blocks 4L..4L+3
    const ulonglong2 hB = bh2[4 * lane + 1];
    const ulonglong2 hC = bh2[4 * lane + 2];
    const ulonglong2 hD = bh2[4 * lane + 3];

    const u64 x1_0 = hA.x,         x1_1 = hA.y;        // excl. within lane
    const u64 x2_0 = x1_0 + hB.x,  x2_1 = x1_1 + hB.y;
    const u64 x3_0 = x2_0 + hC.x,  x3_1 = x2_1 + hC.y;
    const u64 inc0 = x3_0 + hD.x,  inc1 = x3_1 + hD.y;

    u64 s0 = inc0, s1 = inc1;
#pragma unroll
    for (int d = 1; d < 64; d <<= 1) {
        u64 n0 = __shfl_up(s0, d, 64);
        u64 n1 = __shfl_up(s1, d, 64);
        if (lane >= d) { s0 += n0; s1 += n1; }
    }
    const u64 base0 = s0 - inc0, base1 = s1 - inc1;   // excl. across lanes
    const u64 g0 = __shfl(s0, 63, 64);                // packed grand totals
    const u64 g1 = __shfl(s1, 63, 64);

    // packed expert exclusive bases
    unsigned t0e = (unsigned)((g0 >>  0) & 0xFFFF), t1e = (unsigned)((g0 >> 16) & 0xFFFF);
    unsigned t2e = (unsigned)((g0 >> 32) & 0xFFFF), t3e = (unsigned)((g0 >> 48) & 0xFFFF);
    unsigned t4e = (unsigned)((g1 >>  0) & 0xFFFF), t5e = (unsigned)((g1 >> 16) & 0xFFFF);
    unsigned t6e = (unsigned)((g1 >> 32) & 0xFFFF);
    unsigned b0 = 0, b1 = b0 + t0e, b2 = b1 + t1e, b3 = b2 + t2e;
    unsigned b4 = b3 + t3e, b5 = b4 + t4e, b6 = b5 + t5e, b7 = b6 + t6e;
    const u64 pb0 = (u64)b0 | ((u64)b1 << 16) | ((u64)b2 << 32) | ((u64)b3 << 48);
    const u64 pb1 = (u64)b4 | ((u64)b5 << 16) | ((u64)b6 << 32) | ((u64)b7 << 48);

    // this block's packed global offset pair (owner lane b>>2, slot b&3)
    const int owner = b >> 2, sub = b & 3;   // uniform
    u64 sel0, sel1;
    switch (sub) {
        case 0:  sel0 = base0 + pb0;        sel1 = base1 + pb1;        break;
        case 1:  sel0 = base0 + x1_0 + pb0; sel1 = base1 + x1_1 + pb1; break;
        case 2:  sel0 = base0 + x2_0 + pb0; sel1 = base1 + x2_1 + pb1; break;
        default: sel0 = base0 + x3_0 + pb0; sel1 = base1 + x3_1 + pb1; break;
    }
    const u64 o0 = __shfl(sel0, owner, 64);
    const u64 o1 = __shfl(sel1, owner, 64);

    if (b == 0 && lane < NE) {
        const unsigned tv = (unsigned)(((lane < 4) ? (g0 >> (16 * lane))
                                                   : (g1 >> (16 * (lane - 4)))) & 0xFFFFull);
        out[2 * NSLOTS + lane] = (float)tv;
    }

    // ---- scatter own 2 slots ----
    const float2 sc = reinterpret_cast<const float2*>(sLds)[lane];
    const float tokf = (float)(b * 64 + lane);
    const unsigned pA = field_of(o0, o1, ee.x) + rankA;
    const unsigned pB = field_of(o0, o1, ee.y) + rankB;
    out[pA] = sc.x;
    out[NSLOTS + pA] = tokf;
    out[pB] = sc.y;
    out[NSLOTS + pB] = tokf;
}

extern "C" void kernel_launch(void* const* d_in, const int* in_sizes, int n_in,
                              void* d_out, int out_size, void* d_ws, size_t ws_size,
                              hipStream_t stream) {
    const float* x = (const float*)d_in[0];
    const float* W = (const float*)d_in[1];
    float* out = (float*)d_out;
    u64* bh_ws = (u64*)d_ws;   // 4 KiB histograms + 8 B counter

    // deterministically clear histograms + counter each call (graph-capturable)
    hipMemsetAsync(bh_ws, 0, (2 * NB1 + 1) * sizeof(u64), stream);
    router_all<<<dim3(NB1), dim3(1024), 0, stream>>>(x, W, bh_ws, out);
}